// Round 1
// baseline (724.115 us; speedup 1.0000x reference)
//
#include <hip/hip_runtime.h>
#include <cstdint>

#define N_TOK 8192
#define DIM   1024
#define DFF   4096
#define NEXP  8
#define CAP   1280
#define NSLOT (N_TOK * 2)

typedef __attribute__((ext_vector_type(8))) __bf16 bf16x8;
typedef __attribute__((ext_vector_type(4))) float f32x4;
typedef __attribute__((ext_vector_type(8))) unsigned short u16x8;

__device__ __forceinline__ unsigned short f2b(float f) {
  union { float f; unsigned u; } v; v.f = f;
  unsigned r = v.u + 0x7FFFu + ((v.u >> 16) & 1u);
  return (unsigned short)(r >> 16);
}
__device__ __forceinline__ float b2f(unsigned short b) {
  union { unsigned u; float f; } v; v.u = ((unsigned)b) << 16;
  return v.f;
}

// ---------------- gating: fp32-exact logits, top-2, softmax ----------------
__global__ __launch_bounds__(256) void gate_kernel(
    const float* __restrict__ x, const float* __restrict__ Wg,
    int* __restrict__ idx, float* __restrict__ pw)
{
  const int wave = threadIdx.x >> 6, lane = threadIdx.x & 63;
  const int token = blockIdx.x * 4 + wave;
  const float4* xr = (const float4*)(x + (long)token * DIM);
  float4 xv[4];
#pragma unroll
  for (int p = 0; p < 4; ++p) xv[p] = xr[p * 64 + lane];
  float s[8];
#pragma unroll
  for (int e = 0; e < 8; ++e) {
    const float4* wr = (const float4*)(Wg + e * DIM);
    float acc = 0.f;
#pragma unroll
    for (int p = 0; p < 4; ++p) {
      float4 wv = wr[p * 64 + lane];
      acc += xv[p].x * wv.x + xv[p].y * wv.y + xv[p].z * wv.z + xv[p].w * wv.w;
    }
    s[e] = acc;
  }
#pragma unroll
  for (int o = 32; o; o >>= 1)
#pragma unroll
    for (int e = 0; e < 8; ++e) s[e] += __shfl_xor(s[e], o, 64);

  if (lane == 0) {
    int e1 = 0; float s1 = s[0];
#pragma unroll
    for (int e = 1; e < 8; ++e) if (s[e] > s1) { s1 = s[e]; e1 = e; }
    int e2 = -1; float s2 = -1e30f;
#pragma unroll
    for (int e = 0; e < 8; ++e) { if (e == e1) continue; if (s[e] > s2) { s2 = s[e]; e2 = e; } }
    float t = expf(s2 - s1);
    float p1 = 1.f / (1.f + t);
    float p2 = t * p1;
    idx[2 * token] = e1; idx[2 * token + 1] = e2;
    pw[2 * token] = p1;  pw[2 * token + 1] = p2;
  }
}

// ------- ordered capacity scan (single wave: deterministic slot order) -----
__global__ __launch_bounds__(64) void scan_kernel(
    const int* __restrict__ idx, const float* __restrict__ pw,
    int* __restrict__ pos_out, float* __restrict__ w_out,
    float* __restrict__ aux_out)
{
  const int lane = threadIdx.x;
  const unsigned long long below = (1ull << lane) - 1ull;
  int base[8]; float imp[8]; int cnt[8];
#pragma unroll
  for (int q = 0; q < 8; ++q) { base[q] = 0; imp[q] = 0.f; cnt[q] = 0; }

  for (int it = 0; it < NSLOT / 64; ++it) {
    const int s = it * 64 + lane;
    const int e = idx[s];
    const float p = pw[s];
    int mypos = 0;
#pragma unroll
    for (int q = 0; q < 8; ++q) {
      unsigned long long m = __ballot(e == q);
      if (e == q) mypos = base[q] + __popcll(m & below);
      base[q] += __popcll(m);
    }
    const bool keep = mypos < CAP;
    const float wk = keep ? p : 0.f;
    const float wp = __shfl_xor(wk, 1, 64);
    const float wn = wk / (wk + wp + 1e-9f);
    const bool valid = wn > 0.f;
    pos_out[s] = valid ? mypos : -1;
    w_out[s] = wn;
    if (valid) { cnt[e] += 1; imp[e] += wn; }
  }
  // aux loss: sum_e (cnt_e/T)*(imp_e/I) * E
  float c8[8], i8[8], T = 0.f, I = 0.f;
#pragma unroll
  for (int q = 0; q < 8; ++q) {
    float c = (float)cnt[q], im = imp[q];
#pragma unroll
    for (int o = 32; o; o >>= 1) { c += __shfl_xor(c, o, 64); im += __shfl_xor(im, o, 64); }
    c8[q] = c; i8[q] = im; T += c; I += im;
  }
  if (lane == 0) {
    float aux = 0.f;
#pragma unroll
    for (int q = 0; q < 8; ++q) aux += (c8[q] / T) * (i8[q] / I);
    aux_out[0] = aux * 8.f;
  }
}

// ---------------- dispatch: X[e][pos] = x[token] * w (bf16) ----------------
__global__ __launch_bounds__(128) void dispatch_kernel(
    const float* __restrict__ x, const int* __restrict__ idx,
    const int* __restrict__ pos, const float* __restrict__ w,
    unsigned short* __restrict__ X)
{
  const int s = blockIdx.x;
  const int p = pos[s];
  if (p < 0) return;
  const int e = idx[s];
  const float wt = w[s];
  const int t = threadIdx.x;
  const float4* xr = (const float4*)(x + ((long)(s >> 1)) * DIM);
  float4 a = xr[t * 2], b = xr[t * 2 + 1];
  u16x8 o;
  o[0] = f2b(a.x * wt); o[1] = f2b(a.y * wt); o[2] = f2b(a.z * wt); o[3] = f2b(a.w * wt);
  o[4] = f2b(b.x * wt); o[5] = f2b(b.y * wt); o[6] = f2b(b.z * wt); o[7] = f2b(b.w * wt);
  *(u16x8*)(X + ((long)e * CAP + p) * DIM + t * 8) = o;
}

// ---------------- fp32 -> bf16 bulk convert (weights) ----------------------
__global__ __launch_bounds__(256) void f2b_kernel(
    const float* __restrict__ src, unsigned short* __restrict__ dst, int n8)
{
  int i = blockIdx.x * 256 + threadIdx.x;
  const int stride = gridDim.x * 256;
  for (; i < n8; i += stride) {
    const float4* s4 = ((const float4*)src) + (long)i * 2;
    float4 a = s4[0], b = s4[1];
    u16x8 o;
    o[0] = f2b(a.x); o[1] = f2b(a.y); o[2] = f2b(a.z); o[3] = f2b(a.w);
    o[4] = f2b(b.x); o[5] = f2b(b.y); o[6] = f2b(b.z); o[7] = f2b(b.w);
    ((u16x8*)dst)[i] = o;
  }
}

// --------- batched GEMM: C[e] = A[e] (MxK) * B[e]^T (NxK), bf16 out --------
// m97 structure: 128x128 tile, BK=32, global_load_lds width=16, 4 waves 2x2,
// per wave 4x4 accs of 16x16x32 MFMA.
__global__ __launch_bounds__(256, 2) void gemm_bt(
    const unsigned short* __restrict__ A, const unsigned short* __restrict__ B,
    unsigned short* __restrict__ C, int M, int N, int K, int relu)
{
  __shared__ unsigned short As[128 * 32];
  __shared__ unsigned short Bs[128 * 32];
  const int e = blockIdx.z;
  const unsigned short* Ae = A + (long)e * M * K;
  const unsigned short* Be = B + (long)e * N * K;
  unsigned short* Ce = C + (long)e * M * N;
  const int m0 = blockIdx.y * 128, n0 = blockIdx.x * 128;
  const int t = threadIdx.x, wave = t >> 6, lane = t & 63;
  const int wm = (wave >> 1) * 64, wn = (wave & 1) * 64;
  const int rl = lane >> 2, klo = (lane & 3) * 8;   // staging: row-in-chunk, k-offset
  const int fr = lane & 15, fk = (lane >> 4) * 8;   // fragment: row, k-offset

  f32x4 acc[4][4] = {};

  for (int kb = 0; kb < K; kb += 32) {
#pragma unroll
    for (int c = 0; c < 2; ++c) {
      const int chunk = wave * 2 + c;               // 0..7, wave-uniform
      const int row = chunk * 16 + rl;
      const unsigned short* gA = Ae + (long)(m0 + row) * K + kb + klo;
      const unsigned short* gB = Be + (long)(n0 + row) * K + kb + klo;
      __builtin_amdgcn_global_load_lds(
          (const __attribute__((address_space(1))) void*)gA,
          (__attribute__((address_space(3))) void*)(As + chunk * 512), 16, 0, 0);
      __builtin_amdgcn_global_load_lds(
          (const __attribute__((address_space(1))) void*)gB,
          (__attribute__((address_space(3))) void*)(Bs + chunk * 512), 16, 0, 0);
    }
    __syncthreads();   // vmcnt(0) drain of the LDS-DMA + barrier
    bf16x8 af[4], bg[4];
#pragma unroll
    for (int i = 0; i < 4; ++i)
      af[i] = *(const bf16x8*)(As + (wm + i * 16 + fr) * 32 + fk);
#pragma unroll
    for (int j = 0; j < 4; ++j)
      bg[j] = *(const bf16x8*)(Bs + (wn + j * 16 + fr) * 32 + fk);
#pragma unroll
    for (int i = 0; i < 4; ++i)
#pragma unroll
      for (int j = 0; j < 4; ++j)
        acc[i][j] = __builtin_amdgcn_mfma_f32_16x16x32_bf16(af[i], bg[j], acc[i][j], 0, 0, 0);
    __syncthreads();   // protect LDS before next stage
  }

  // epilogue: C/D layout col=lane&15, row=(lane>>4)*4+reg  [m89/m91 verified]
  const int rr = (lane >> 4) * 4, cc = lane & 15;
#pragma unroll
  for (int i = 0; i < 4; ++i)
#pragma unroll
    for (int j = 0; j < 4; ++j)
#pragma unroll
      for (int r = 0; r < 4; ++r) {
        float v = acc[i][j][r];
        if (relu) v = fmaxf(v, 0.f);
        Ce[(long)(m0 + wm + i * 16 + rr + r) * N + (n0 + wn + j * 16 + cc)] = f2b(v);
      }
}

// ---------------- combine: y[token] = sum of its valid slot rows -----------
__global__ __launch_bounds__(128) void combine_kernel(
    const unsigned short* __restrict__ Y, const int* __restrict__ idx,
    const int* __restrict__ pos, float* __restrict__ y)
{
  const int n = blockIdx.x, t = threadIdx.x;
  const int p0 = pos[2 * n], p1 = pos[2 * n + 1];
  float a[8] = {0.f, 0.f, 0.f, 0.f, 0.f, 0.f, 0.f, 0.f};
  if (p0 >= 0) {
    const int e = idx[2 * n];
    u16x8 v = *(const u16x8*)(Y + ((long)e * CAP + p0) * DIM + t * 8);
#pragma unroll
    for (int r = 0; r < 8; ++r) a[r] += b2f(v[r]);
  }
  if (p1 >= 0) {
    const int e = idx[2 * n + 1];
    u16x8 v = *(const u16x8*)(Y + ((long)e * CAP + p1) * DIM + t * 8);
#pragma unroll
    for (int r = 0; r < 8; ++r) a[r] += b2f(v[r]);
  }
  float4* out = (float4*)(y + (long)n * DIM + t * 8);
  out[0] = make_float4(a[0], a[1], a[2], a[3]);
  out[1] = make_float4(a[4], a[5], a[6], a[7]);
}

extern "C" void kernel_launch(void* const* d_in, const int* in_sizes, int n_in,
                              void* d_out, int out_size, void* d_ws, size_t ws_size,
                              hipStream_t stream)
{
  const float* x  = (const float*)d_in[0];
  const float* Wg = (const float*)d_in[1];
  const float* W1 = (const float*)d_in[2];
  const float* W2 = (const float*)d_in[3];
  float* y   = (float*)d_out;
  float* aux = y + (long)N_TOK * DIM;

  char* ws = (char*)d_ws;
  size_t off = 0;
  auto alloc = [&](size_t bytes) -> void* {
    void* p = ws + off;
    off = (off + bytes + 255) & ~(size_t)255;
    return p;
  };
  int*            idx = (int*)alloc(NSLOT * 4);
  float*          pw  = (float*)alloc(NSLOT * 4);
  int*            pos = (int*)alloc(NSLOT * 4);
  float*          w   = (float*)alloc(NSLOT * 4);
  unsigned short* Xbf = (unsigned short*)alloc((size_t)NEXP * CAP * DIM * 2);
  unsigned short* Hbf = (unsigned short*)alloc((size_t)NEXP * CAP * DFF * 2);
  unsigned short* Ybf = (unsigned short*)alloc((size_t)NEXP * CAP * DIM * 2);
  unsigned short* Wbf = (unsigned short*)alloc((size_t)NEXP * DFF * DIM * 2); // shared W1/W2

  gate_kernel<<<N_TOK / 4, 256, 0, stream>>>(x, Wg, idx, pw);
  scan_kernel<<<1, 64, 0, stream>>>(idx, pw, pos, w, aux);
  dispatch_kernel<<<NSLOT, 128, 0, stream>>>(x, idx, pos, w, Xbf);

  f2b_kernel<<<8192, 256, 0, stream>>>(W1, Wbf, NEXP * DFF * DIM / 8);
  gemm_bt<<<dim3(DFF / 128, CAP / 128, NEXP), 256, 0, stream>>>(Xbf, Wbf, Hbf, CAP, DFF, DIM, 1);

  f2b_kernel<<<8192, 256, 0, stream>>>(W2, Wbf, NEXP * DIM * DFF / 8);
  gemm_bt<<<dim3(DIM / 128, CAP / 128, NEXP), 256, 0, stream>>>(Hbf, Wbf, Ybf, CAP, DIM, DFF, 0);

  combine_kernel<<<N_TOK, 128, 0, stream>>>(Ybf, idx, pos, y);
}

// Round 2
// 612.703 us; speedup vs baseline: 1.1818x; 1.1818x over previous
//
#include <hip/hip_runtime.h>
#include <cstdint>

#define N_TOK 8192
#define DIM   1024
#define DFF   4096
#define NEXP  8
#define CAP   1280
#define NSLOT (N_TOK * 2)
#define SCAN_WAVES 16

typedef __attribute__((ext_vector_type(8))) __bf16 bf16x8;
typedef __attribute__((ext_vector_type(4))) float f32x4;
typedef __attribute__((ext_vector_type(8))) unsigned short u16x8;

__device__ __forceinline__ unsigned short f2b(float f) {
  union { float f; unsigned u; } v; v.f = f;
  unsigned r = v.u + 0x7FFFu + ((v.u >> 16) & 1u);
  return (unsigned short)(r >> 16);
}
__device__ __forceinline__ float b2f(unsigned short b) {
  union { unsigned u; float f; } v; v.u = ((unsigned)b) << 16;
  return v.f;
}

// ---------------- gating: fp32-exact logits, top-2, softmax ----------------
__global__ __launch_bounds__(256) void gate_kernel(
    const float* __restrict__ x, const float* __restrict__ Wg,
    int* __restrict__ idx, float* __restrict__ pw)
{
  const int wave = threadIdx.x >> 6, lane = threadIdx.x & 63;
  const int token = blockIdx.x * 4 + wave;
  const float4* xr = (const float4*)(x + (long)token * DIM);
  float4 xv[4];
#pragma unroll
  for (int p = 0; p < 4; ++p) xv[p] = xr[p * 64 + lane];
  float s[8];
#pragma unroll
  for (int e = 0; e < 8; ++e) {
    const float4* wr = (const float4*)(Wg + e * DIM);
    float acc = 0.f;
#pragma unroll
    for (int p = 0; p < 4; ++p) {
      float4 wv = wr[p * 64 + lane];
      acc += xv[p].x * wv.x + xv[p].y * wv.y + xv[p].z * wv.z + xv[p].w * wv.w;
    }
    s[e] = acc;
  }
#pragma unroll
  for (int o = 32; o; o >>= 1)
#pragma unroll
    for (int e = 0; e < 8; ++e) s[e] += __shfl_xor(s[e], o, 64);

  if (lane == 0) {
    int e1 = 0; float s1 = s[0];
#pragma unroll
    for (int e = 1; e < 8; ++e) if (s[e] > s1) { s1 = s[e]; e1 = e; }
    int e2 = -1; float s2 = -1e30f;
#pragma unroll
    for (int e = 0; e < 8; ++e) { if (e == e1) continue; if (s[e] > s2) { s2 = s[e]; e2 = e; } }
    float t = expf(s2 - s1);
    float p1 = 1.f / (1.f + t);
    float p2 = t * p1;
    idx[2 * token] = e1; idx[2 * token + 1] = e2;
    pw[2 * token] = p1;  pw[2 * token + 1] = p2;
  }
}

// ------- ordered capacity scan: 16 waves, wave-local scan + prefix ---------
__global__ __launch_bounds__(1024) void scan_kernel(
    const int* __restrict__ idx, const float* __restrict__ pw,
    int* __restrict__ pos_out, float* __restrict__ w_out,
    float* __restrict__ aux_out)
{
  __shared__ int wcnt[SCAN_WAVES * 8];
  __shared__ int woff[SCAN_WAVES * 8];
  __shared__ float redc[SCAN_WAVES * 8];
  __shared__ float redi[SCAN_WAVES * 8];
  const int t = threadIdx.x, w = t >> 6, lane = t & 63;
  const unsigned long long below = (1ull << lane) - 1ull;
  const int base_s = w * (NSLOT / SCAN_WAVES);   // 1024 slots per wave, in order

  int e_r[16]; float p_r[16]; int lp_r[16];
  int base[8] = {0, 0, 0, 0, 0, 0, 0, 0};
  for (int r = 0; r < 16; ++r) {
    const int s = base_s + r * 64 + lane;
    const int e = idx[s];
    const float p = pw[s];
    e_r[r] = e; p_r[r] = p;
    int mypos = 0;
#pragma unroll
    for (int q = 0; q < 8; ++q) {
      unsigned long long m = __ballot(e == q);
      if (e == q) mypos = base[q] + __popcll(m & below);
      base[q] += __popcll(m);
    }
    lp_r[r] = mypos;
  }
  if (lane < 8) wcnt[w * 8 + lane] = base[lane];
  __syncthreads();
  if (t < SCAN_WAVES * 8) {
    const int ww = t >> 3, q = t & 7;
    int acc = 0;
    for (int w2 = 0; w2 < ww; ++w2) acc += wcnt[w2 * 8 + q];
    woff[t] = acc;
  }
  __syncthreads();
  int off8[8];
#pragma unroll
  for (int q = 0; q < 8; ++q) off8[q] = woff[w * 8 + q];

  float cnt[8] = {0, 0, 0, 0, 0, 0, 0, 0};
  float imp[8] = {0, 0, 0, 0, 0, 0, 0, 0};
  for (int r = 0; r < 16; ++r) {
    const int s = base_s + r * 64 + lane;
    const int e = e_r[r];
    const int gpos = off8[e] + lp_r[r];
    const bool keep = gpos < CAP;
    const float wk = keep ? p_r[r] : 0.f;
    const float wp = __shfl_xor(wk, 1, 64);
    const float wn = wk / (wk + wp + 1e-9f);
    const bool valid = wn > 0.f;
    pos_out[s] = valid ? gpos : -1;
    w_out[s] = wn;
    if (valid) { cnt[e] += 1.f; imp[e] += wn; }
  }
#pragma unroll
  for (int q = 0; q < 8; ++q)
#pragma unroll
    for (int o = 32; o; o >>= 1) {
      cnt[q] += __shfl_xor(cnt[q], o, 64);
      imp[q] += __shfl_xor(imp[q], o, 64);
    }
  if (lane < 8) { redc[w * 8 + lane] = cnt[lane]; redi[w * 8 + lane] = imp[lane]; }
  __syncthreads();
  if (t == 0) {
    float c8[8] = {0, 0, 0, 0, 0, 0, 0, 0};
    float i8[8] = {0, 0, 0, 0, 0, 0, 0, 0};
    float T = 0.f, I = 0.f;
    for (int w2 = 0; w2 < SCAN_WAVES; ++w2)
      for (int q = 0; q < 8; ++q) { c8[q] += redc[w2 * 8 + q]; i8[q] += redi[w2 * 8 + q]; }
    for (int q = 0; q < 8; ++q) { T += c8[q]; I += i8[q]; }
    float aux = 0.f;
    for (int q = 0; q < 8; ++q) aux += (c8[q] / T) * (i8[q] / I);
    aux_out[0] = aux * 8.f;
  }
}

// ---------------- dispatch: X[e][pos] = x[token] * w (bf16) ----------------
__global__ __launch_bounds__(128) void dispatch_kernel(
    const float* __restrict__ x, const int* __restrict__ idx,
    const int* __restrict__ pos, const float* __restrict__ w,
    unsigned short* __restrict__ X)
{
  const int s = blockIdx.x;
  const int p = pos[s];
  if (p < 0) return;
  const int e = idx[s];
  const float wt = w[s];
  const int t = threadIdx.x;
  const float4* xr = (const float4*)(x + ((long)(s >> 1)) * DIM);
  float4 a = xr[t * 2], b = xr[t * 2 + 1];
  u16x8 o;
  o[0] = f2b(a.x * wt); o[1] = f2b(a.y * wt); o[2] = f2b(a.z * wt); o[3] = f2b(a.w * wt);
  o[4] = f2b(b.x * wt); o[5] = f2b(b.y * wt); o[6] = f2b(b.z * wt); o[7] = f2b(b.w * wt);
  *(u16x8*)(X + ((long)e * CAP + p) * DIM + t * 8) = o;
}

// ---------------- fp32 -> bf16 bulk convert (weights) ----------------------
__global__ __launch_bounds__(256) void f2b_kernel(
    const float* __restrict__ src, unsigned short* __restrict__ dst, int n8)
{
  int i = blockIdx.x * 256 + threadIdx.x;
  const int stride = gridDim.x * 256;
  for (; i < n8; i += stride) {
    const float4* s4 = ((const float4*)src) + (long)i * 2;
    float4 a = s4[0], b = s4[1];
    u16x8 o;
    o[0] = f2b(a.x); o[1] = f2b(a.y); o[2] = f2b(a.z); o[3] = f2b(a.w);
    o[4] = f2b(b.x); o[5] = f2b(b.y); o[6] = f2b(b.z); o[7] = f2b(b.w);
    ((u16x8*)dst)[i] = o;
  }
}

// --------- batched GEMM: C[e] = A[e] (MxK) * B[e]^T (NxK), bf16 out --------
// m97 structure + XOR k-quarter swizzle: staging lane for row r loads global
// quarter (q ^ ((r>>1)&3)); fragment read indexes the matching LDS slot.
// Spreads 16-lane ds_read_b128 over 8 distinct 128B slots (2-way = free).
__global__ __launch_bounds__(256, 2) void gemm_bt(
    const unsigned short* __restrict__ A, const unsigned short* __restrict__ B,
    unsigned short* __restrict__ C, int M, int N, int K, int relu)
{
  __shared__ unsigned short As[128 * 32];
  __shared__ unsigned short Bs[128 * 32];
  const int e = blockIdx.z;
  const unsigned short* Ae = A + (long)e * M * K;
  const unsigned short* Be = B + (long)e * N * K;
  unsigned short* Ce = C + (long)e * M * N;
  const int m0 = blockIdx.y * 128, n0 = blockIdx.x * 128;
  const int t = threadIdx.x, wave = t >> 6, lane = t & 63;
  const int wm = (wave >> 1) * 64, wn = (wave & 1) * 64;
  const int rl = lane >> 2, ql = lane & 3;          // staging: row-in-chunk, LDS quarter
  const int qg = ql ^ ((rl >> 1) & 3);              // global quarter (swizzled)
  const int klo = qg * 8;
  const int fr = lane & 15;                         // fragment: row
  const int qw = lane >> 4;                         // fragment: wanted global quarter
  const int qs = qw ^ ((fr >> 1) & 3);              // LDS quarter slot holding it

  f32x4 acc[4][4] = {};

  for (int kb = 0; kb < K; kb += 32) {
#pragma unroll
    for (int c = 0; c < 2; ++c) {
      const int chunk = wave * 2 + c;               // 0..7, wave-uniform
      const int row = chunk * 16 + rl;
      const unsigned short* gA = Ae + (long)(m0 + row) * K + kb + klo;
      const unsigned short* gB = Be + (long)(n0 + row) * K + kb + klo;
      __builtin_amdgcn_global_load_lds(
          (const __attribute__((address_space(1))) void*)gA,
          (__attribute__((address_space(3))) void*)(As + chunk * 512), 16, 0, 0);
      __builtin_amdgcn_global_load_lds(
          (const __attribute__((address_space(1))) void*)gB,
          (__attribute__((address_space(3))) void*)(Bs + chunk * 512), 16, 0, 0);
    }
    __syncthreads();
    bf16x8 af[4], bg[4];
#pragma unroll
    for (int i = 0; i < 4; ++i)
      af[i] = *(const bf16x8*)(As + (wm + i * 16 + fr) * 32 + qs * 8);
#pragma unroll
    for (int j = 0; j < 4; ++j)
      bg[j] = *(const bf16x8*)(Bs + (wn + j * 16 + fr) * 32 + qs * 8);
#pragma unroll
    for (int i = 0; i < 4; ++i)
#pragma unroll
      for (int j = 0; j < 4; ++j)
        acc[i][j] = __builtin_amdgcn_mfma_f32_16x16x32_bf16(af[i], bg[j], acc[i][j], 0, 0, 0);
    __syncthreads();
  }

  // epilogue: C/D layout col=lane&15, row=(lane>>4)*4+reg  [m89/m91 verified]
  const int rr = (lane >> 4) * 4, cc = lane & 15;
#pragma unroll
  for (int i = 0; i < 4; ++i)
#pragma unroll
    for (int j = 0; j < 4; ++j)
#pragma unroll
      for (int r = 0; r < 4; ++r) {
        float v = acc[i][j][r];
        if (relu) v = fmaxf(v, 0.f);
        Ce[(long)(m0 + wm + i * 16 + rr + r) * N + (n0 + wn + j * 16 + cc)] = f2b(v);
      }
}

// ---------------- combine: y[token] = sum of its valid slot rows -----------
__global__ __launch_bounds__(128) void combine_kernel(
    const unsigned short* __restrict__ Y, const int* __restrict__ idx,
    const int* __restrict__ pos, float* __restrict__ y)
{
  const int n = blockIdx.x, t = threadIdx.x;
  const int p0 = pos[2 * n], p1 = pos[2 * n + 1];
  float a[8] = {0.f, 0.f, 0.f, 0.f, 0.f, 0.f, 0.f, 0.f};
  if (p0 >= 0) {
    const int e = idx[2 * n];
    u16x8 v = *(const u16x8*)(Y + ((long)e * CAP + p0) * DIM + t * 8);
#pragma unroll
    for (int r = 0; r < 8; ++r) a[r] += b2f(v[r]);
  }
  if (p1 >= 0) {
    const int e = idx[2 * n + 1];
    u16x8 v = *(const u16x8*)(Y + ((long)e * CAP + p1) * DIM + t * 8);
#pragma unroll
    for (int r = 0; r < 8; ++r) a[r] += b2f(v[r]);
  }
  float4* out = (float4*)(y + (long)n * DIM + t * 8);
  out[0] = make_float4(a[0], a[1], a[2], a[3]);
  out[1] = make_float4(a[4], a[5], a[6], a[7]);
}

extern "C" void kernel_launch(void* const* d_in, const int* in_sizes, int n_in,
                              void* d_out, int out_size, void* d_ws, size_t ws_size,
                              hipStream_t stream)
{
  const float* x  = (const float*)d_in[0];
  const float* Wg = (const float*)d_in[1];
  const float* W1 = (const float*)d_in[2];
  const float* W2 = (const float*)d_in[3];
  float* y   = (float*)d_out;
  float* aux = y + (long)N_TOK * DIM;

  char* ws = (char*)d_ws;
  size_t off = 0;
  auto alloc = [&](size_t bytes) -> void* {
    void* p = ws + off;
    off = (off + bytes + 255) & ~(size_t)255;
    return p;
  };
  int*            idx = (int*)alloc(NSLOT * 4);
  float*          pw  = (float*)alloc(NSLOT * 4);
  int*            pos = (int*)alloc(NSLOT * 4);
  float*          w   = (float*)alloc(NSLOT * 4);
  unsigned short* Xbf = (unsigned short*)alloc((size_t)NEXP * CAP * DIM * 2);
  unsigned short* Hbf = (unsigned short*)alloc((size_t)NEXP * CAP * DFF * 2);
  unsigned short* Ybf = (unsigned short*)alloc((size_t)NEXP * CAP * DIM * 2);
  unsigned short* Wbf = (unsigned short*)alloc((size_t)NEXP * DFF * DIM * 2); // shared W1/W2

  gate_kernel<<<N_TOK / 4, 256, 0, stream>>>(x, Wg, idx, pw);
  scan_kernel<<<1, 1024, 0, stream>>>(idx, pw, pos, w, aux);
  dispatch_kernel<<<NSLOT, 128, 0, stream>>>(x, idx, pos, w, Xbf);

  f2b_kernel<<<8192, 256, 0, stream>>>(W1, Wbf, NEXP * DFF * DIM / 8);
  gemm_bt<<<dim3(DFF / 128, CAP / 128, NEXP), 256, 0, stream>>>(Xbf, Wbf, Hbf, CAP, DFF, DIM, 1);

  f2b_kernel<<<8192, 256, 0, stream>>>(W2, Wbf, NEXP * DIM * DFF / 8);
  gemm_bt<<<dim3(DIM / 128, CAP / 128, NEXP), 256, 0, stream>>>(Hbf, Wbf, Ybf, CAP, DIM, DFF, 0);

  combine_kernel<<<N_TOK, 128, 0, stream>>>(Ybf, idx, pos, y);
}

// Round 3
// 593.804 us; speedup vs baseline: 1.2195x; 1.0318x over previous
//
#include <hip/hip_runtime.h>
#include <cstdint>

#define N_TOK 8192
#define DIM   1024
#define DFF   4096
#define NEXP  8
#define CAP   1280
#define NSLOT (N_TOK * 2)
#define SCAN_WAVES 16

typedef __attribute__((ext_vector_type(8))) __bf16 bf16x8;
typedef __attribute__((ext_vector_type(4))) float f32x4;
typedef __attribute__((ext_vector_type(8))) unsigned short u16x8;

__device__ __forceinline__ unsigned short f2b(float f) {
  union { float f; unsigned u; } v; v.f = f;
  unsigned r = v.u + 0x7FFFu + ((v.u >> 16) & 1u);
  return (unsigned short)(r >> 16);
}
__device__ __forceinline__ float b2f(unsigned short b) {
  union { unsigned u; float f; } v; v.u = ((unsigned)b) << 16;
  return v.f;
}

__device__ __forceinline__ void f2b_body(const float* __restrict__ src,
                                         unsigned short* __restrict__ dst,
                                         int n8, int b, int nb) {
  int i = b * 256 + (threadIdx.x & 255);
  const int stride = nb * 256;
  for (; i < n8; i += stride) {
    const float4* s4 = ((const float4*)src) + (long)i * 2;
    float4 a = s4[0], c = s4[1];
    u16x8 o;
    o[0] = f2b(a.x); o[1] = f2b(a.y); o[2] = f2b(a.z); o[3] = f2b(a.w);
    o[4] = f2b(c.x); o[5] = f2b(c.y); o[6] = f2b(c.z); o[7] = f2b(c.w);
    ((u16x8*)dst)[i] = o;
  }
}

// -------- gating (fp32-exact) + fused f2b(W1) in trailing blocks -----------
__global__ __launch_bounds__(256) void gate_kernel(
    const float* __restrict__ x, const float* __restrict__ Wg,
    int* __restrict__ idx, float* __restrict__ pw,
    const float* __restrict__ fsrc, unsigned short* __restrict__ fdst,
    int n8, int ngate)
{
  if ((int)blockIdx.x >= ngate) {
    f2b_body(fsrc, fdst, n8, blockIdx.x - ngate, gridDim.x - ngate);
    return;
  }
  const int wave = threadIdx.x >> 6, lane = threadIdx.x & 63;
  const int token = blockIdx.x * 4 + wave;
  const float4* xr = (const float4*)(x + (long)token * DIM);
  float4 xv[4];
#pragma unroll
  for (int p = 0; p < 4; ++p) xv[p] = xr[p * 64 + lane];
  float s[8];
#pragma unroll
  for (int e = 0; e < 8; ++e) {
    const float4* wr = (const float4*)(Wg + e * DIM);
    float acc = 0.f;
#pragma unroll
    for (int p = 0; p < 4; ++p) {
      float4 wv = wr[p * 64 + lane];
      acc += xv[p].x * wv.x + xv[p].y * wv.y + xv[p].z * wv.z + xv[p].w * wv.w;
    }
    s[e] = acc;
  }
#pragma unroll
  for (int o = 32; o; o >>= 1)
#pragma unroll
    for (int e = 0; e < 8; ++e) s[e] += __shfl_xor(s[e], o, 64);

  if (lane == 0) {
    int e1 = 0; float s1 = s[0];
#pragma unroll
    for (int e = 1; e < 8; ++e) if (s[e] > s1) { s1 = s[e]; e1 = e; }
    int e2 = -1; float s2 = -1e30f;
#pragma unroll
    for (int e = 0; e < 8; ++e) { if (e == e1) continue; if (s[e] > s2) { s2 = s[e]; e2 = e; } }
    float t = expf(s2 - s1);
    float p1 = 1.f / (1.f + t);
    float p2 = t * p1;
    idx[2 * token] = e1; idx[2 * token + 1] = e2;
    pw[2 * token] = p1;  pw[2 * token + 1] = p2;
  }
}

// ------- ordered capacity scan: 16 waves, wave-local scan + prefix ---------
__global__ __launch_bounds__(1024) void scan_kernel(
    const int* __restrict__ idx, const float* __restrict__ pw,
    int* __restrict__ pos_out, float* __restrict__ w_out,
    float* __restrict__ aux_out)
{
  __shared__ int wcnt[SCAN_WAVES * 8];
  __shared__ int woff[SCAN_WAVES * 8];
  __shared__ float redc[SCAN_WAVES * 8];
  __shared__ float redi[SCAN_WAVES * 8];
  const int t = threadIdx.x, w = t >> 6, lane = t & 63;
  const unsigned long long below = (1ull << lane) - 1ull;
  const int base_s = w * (NSLOT / SCAN_WAVES);

  int e_r[16]; float p_r[16]; int lp_r[16];
  int base[8] = {0, 0, 0, 0, 0, 0, 0, 0};
  for (int r = 0; r < 16; ++r) {
    const int s = base_s + r * 64 + lane;
    const int e = idx[s];
    const float p = pw[s];
    e_r[r] = e; p_r[r] = p;
    int mypos = 0;
#pragma unroll
    for (int q = 0; q < 8; ++q) {
      unsigned long long m = __ballot(e == q);
      if (e == q) mypos = base[q] + __popcll(m & below);
      base[q] += __popcll(m);
    }
    lp_r[r] = mypos;
  }
  if (lane < 8) wcnt[w * 8 + lane] = base[lane];
  __syncthreads();
  if (t < SCAN_WAVES * 8) {
    const int ww = t >> 3, q = t & 7;
    int acc = 0;
    for (int w2 = 0; w2 < ww; ++w2) acc += wcnt[w2 * 8 + q];
    woff[t] = acc;
  }
  __syncthreads();
  int off8[8];
#pragma unroll
  for (int q = 0; q < 8; ++q) off8[q] = woff[w * 8 + q];

  float cnt[8] = {0, 0, 0, 0, 0, 0, 0, 0};
  float imp[8] = {0, 0, 0, 0, 0, 0, 0, 0};
  for (int r = 0; r < 16; ++r) {
    const int s = base_s + r * 64 + lane;
    const int e = e_r[r];
    const int gpos = off8[e] + lp_r[r];
    const bool keep = gpos < CAP;
    const float wk = keep ? p_r[r] : 0.f;
    const float wp = __shfl_xor(wk, 1, 64);
    const float wn = wk / (wk + wp + 1e-9f);
    const bool valid = wn > 0.f;
    pos_out[s] = valid ? gpos : -1;
    w_out[s] = wn;
    if (valid) { cnt[e] += 1.f; imp[e] += wn; }
  }
#pragma unroll
  for (int q = 0; q < 8; ++q)
#pragma unroll
    for (int o = 32; o; o >>= 1) {
      cnt[q] += __shfl_xor(cnt[q], o, 64);
      imp[q] += __shfl_xor(imp[q], o, 64);
    }
  if (lane < 8) { redc[w * 8 + lane] = cnt[lane]; redi[w * 8 + lane] = imp[lane]; }
  __syncthreads();
  if (t == 0) {
    float c8[8] = {0, 0, 0, 0, 0, 0, 0, 0};
    float i8[8] = {0, 0, 0, 0, 0, 0, 0, 0};
    float T = 0.f, I = 0.f;
    for (int w2 = 0; w2 < SCAN_WAVES; ++w2)
      for (int q = 0; q < 8; ++q) { c8[q] += redc[w2 * 8 + q]; i8[q] += redi[w2 * 8 + q]; }
    for (int q = 0; q < 8; ++q) { T += c8[q]; I += i8[q]; }
    float aux = 0.f;
    for (int q = 0; q < 8; ++q) aux += (c8[q] / T) * (i8[q] / I);
    aux_out[0] = aux * 8.f;
  }
}

// ---------------- dispatch: X[e][pos] = x[token] * w (bf16) ----------------
__global__ __launch_bounds__(128) void dispatch_kernel(
    const float* __restrict__ x, const int* __restrict__ idx,
    const int* __restrict__ pos, const float* __restrict__ w,
    unsigned short* __restrict__ X)
{
  const int s = blockIdx.x;
  const int p = pos[s];
  if (p < 0) return;
  const int e = idx[s];
  const float wt = w[s];
  const int t = threadIdx.x;
  const float4* xr = (const float4*)(x + ((long)(s >> 1)) * DIM);
  float4 a = xr[t * 2], b = xr[t * 2 + 1];
  u16x8 o;
  o[0] = f2b(a.x * wt); o[1] = f2b(a.y * wt); o[2] = f2b(a.z * wt); o[3] = f2b(a.w * wt);
  o[4] = f2b(b.x * wt); o[5] = f2b(b.y * wt); o[6] = f2b(b.z * wt); o[7] = f2b(b.w * wt);
  *(u16x8*)(X + ((long)e * CAP + p) * DIM + t * 8) = o;
}

// ---------------- standalone fp32 -> bf16 (fallback path) ------------------
__global__ __launch_bounds__(256) void f2b_kernel(
    const float* __restrict__ src, unsigned short* __restrict__ dst, int n8)
{
  f2b_body(src, dst, n8, blockIdx.x, gridDim.x);
}

// --------- batched GEMM: C[e] = A[e] (MxK) * B[e]^T (NxK), bf16 out --------
// Double-buffered LDS + early prefetch (1 barrier/iter), XCD-pinned 1D grid
// (e = bid&7, m fastest), XOR k-quarter swizzle. Trailing blocks: f2b fuse.
__global__ __launch_bounds__(256, 4) void gemm_bt(
    const unsigned short* __restrict__ A, const unsigned short* __restrict__ B,
    unsigned short* __restrict__ C, int M, int N, int K, int relu,
    int Mt, int nGemm,
    const float* __restrict__ fsrc, unsigned short* __restrict__ fdst, int n8)
{
  __shared__ unsigned short As[2][128 * 32];
  __shared__ unsigned short Bs[2][128 * 32];
  const int bid = blockIdx.x;
  if (bid >= nGemm) {
    f2b_body(fsrc, fdst, n8, bid - nGemm, gridDim.x - nGemm);
    return;
  }
  const int e = bid & 7;
  const int slot = bid >> 3;
  const int m0 = (slot % Mt) * 128, n0 = (slot / Mt) * 128;
  const unsigned short* Ae = A + (long)e * M * K;
  const unsigned short* Be = B + (long)e * N * K;
  unsigned short* Ce = C + (long)e * M * N;
  const int t = threadIdx.x, wave = t >> 6, lane = t & 63;
  const int wm = (wave >> 1) * 64, wn = (wave & 1) * 64;
  const int rl = lane >> 2, ql = lane & 3;          // staging: row-in-chunk, LDS quarter
  const int qg = ql ^ ((rl >> 1) & 3);              // global quarter (swizzled)
  const int klo = qg * 8;
  const int fr = lane & 15;                         // fragment: row
  const int qw = lane >> 4;                         // fragment: wanted global quarter
  const int qs = qw ^ ((fr >> 1) & 3);              // LDS quarter slot holding it

  f32x4 acc[4][4] = {};

  const int c0 = wave * 2, c1 = wave * 2 + 1;
  const int row0 = c0 * 16 + rl, row1 = c1 * 16 + rl;
  const unsigned short* gA0 = Ae + (long)(m0 + row0) * K + klo;
  const unsigned short* gA1 = Ae + (long)(m0 + row1) * K + klo;
  const unsigned short* gB0 = Be + (long)(n0 + row0) * K + klo;
  const unsigned short* gB1 = Be + (long)(n0 + row1) * K + klo;

  auto stage = [&](int p, int kb) {
    __builtin_amdgcn_global_load_lds(
        (const __attribute__((address_space(1))) void*)(gA0 + kb),
        (__attribute__((address_space(3))) void*)(&As[p][c0 * 512]), 16, 0, 0);
    __builtin_amdgcn_global_load_lds(
        (const __attribute__((address_space(1))) void*)(gB0 + kb),
        (__attribute__((address_space(3))) void*)(&Bs[p][c0 * 512]), 16, 0, 0);
    __builtin_amdgcn_global_load_lds(
        (const __attribute__((address_space(1))) void*)(gA1 + kb),
        (__attribute__((address_space(3))) void*)(&As[p][c1 * 512]), 16, 0, 0);
    __builtin_amdgcn_global_load_lds(
        (const __attribute__((address_space(1))) void*)(gB1 + kb),
        (__attribute__((address_space(3))) void*)(&Bs[p][c1 * 512]), 16, 0, 0);
  };

  stage(0, 0);
  int p = 0;
  for (int kb = 0; kb < K; kb += 32) {
    __syncthreads();                 // drains own DMA: buf p ready
    if (kb + 32 < K) stage(p ^ 1, kb + 32);   // early prefetch for next iter
    bf16x8 af[4], bg[4];
#pragma unroll
    for (int i = 0; i < 4; ++i)
      af[i] = *(const bf16x8*)(&As[p][(wm + i * 16 + fr) * 32 + qs * 8]);
#pragma unroll
    for (int j = 0; j < 4; ++j)
      bg[j] = *(const bf16x8*)(&Bs[p][(wn + j * 16 + fr) * 32 + qs * 8]);
#pragma unroll
    for (int i = 0; i < 4; ++i)
#pragma unroll
      for (int j = 0; j < 4; ++j)
        acc[i][j] = __builtin_amdgcn_mfma_f32_16x16x32_bf16(af[i], bg[j], acc[i][j], 0, 0, 0);
    p ^= 1;
  }

  // epilogue: C/D layout col=lane&15, row=(lane>>4)*4+reg  [m89/m91 verified]
  const int rr = (lane >> 4) * 4, cc = lane & 15;
#pragma unroll
  for (int i = 0; i < 4; ++i)
#pragma unroll
    for (int j = 0; j < 4; ++j)
#pragma unroll
      for (int r = 0; r < 4; ++r) {
        float v = acc[i][j][r];
        if (relu) v = fmaxf(v, 0.f);
        Ce[(long)(m0 + wm + i * 16 + rr + r) * N + (n0 + wn + j * 16 + cc)] = f2b(v);
      }
}

// ---------------- combine: y[token] = sum of its valid slot rows -----------
__global__ __launch_bounds__(128) void combine_kernel(
    const unsigned short* __restrict__ Y, const int* __restrict__ idx,
    const int* __restrict__ pos, float* __restrict__ y)
{
  const int n = blockIdx.x, t = threadIdx.x;
  const int p0 = pos[2 * n], p1 = pos[2 * n + 1];
  float a[8] = {0.f, 0.f, 0.f, 0.f, 0.f, 0.f, 0.f, 0.f};
  if (p0 >= 0) {
    const int e = idx[2 * n];
    u16x8 v = *(const u16x8*)(Y + ((long)e * CAP + p0) * DIM + t * 8);
#pragma unroll
    for (int r = 0; r < 8; ++r) a[r] += b2f(v[r]);
  }
  if (p1 >= 0) {
    const int e = idx[2 * n + 1];
    u16x8 v = *(const u16x8*)(Y + ((long)e * CAP + p1) * DIM + t * 8);
#pragma unroll
    for (int r = 0; r < 8; ++r) a[r] += b2f(v[r]);
  }
  float4* out = (float4*)(y + (long)n * DIM + t * 8);
  out[0] = make_float4(a[0], a[1], a[2], a[3]);
  out[1] = make_float4(a[4], a[5], a[6], a[7]);
}

extern "C" void kernel_launch(void* const* d_in, const int* in_sizes, int n_in,
                              void* d_out, int out_size, void* d_ws, size_t ws_size,
                              hipStream_t stream)
{
  const float* x  = (const float*)d_in[0];
  const float* Wg = (const float*)d_in[1];
  const float* W1 = (const float*)d_in[2];
  const float* W2 = (const float*)d_in[3];
  float* y   = (float*)d_out;
  float* aux = y + (long)N_TOK * DIM;

  char* ws = (char*)d_ws;
  size_t off = 0;
  auto alloc = [&](size_t bytes) -> void* {
    void* p = ws + off;
    off = (off + bytes + 255) & ~(size_t)255;
    return p;
  };
  int*            idx  = (int*)alloc(NSLOT * 4);
  float*          pw   = (float*)alloc(NSLOT * 4);
  int*            pos  = (int*)alloc(NSLOT * 4);
  float*          w    = (float*)alloc(NSLOT * 4);
  unsigned short* Xbf  = (unsigned short*)alloc((size_t)NEXP * CAP * DIM * 2);
  unsigned short* Hbf  = (unsigned short*)alloc((size_t)NEXP * CAP * DFF * 2);
  unsigned short* Ybf  = (unsigned short*)alloc((size_t)NEXP * CAP * DIM * 2);
  unsigned short* Wbf1 = (unsigned short*)alloc((size_t)NEXP * DFF * DIM * 2);
  size_t off_small = off;
  unsigned short* Wbf2 = (unsigned short*)alloc((size_t)NEXP * DFF * DIM * 2);
  const bool big = ws_size >= off;          // ws_size constant across calls
  (void)off_small;

  const int n8w = NEXP * DFF * DIM / 8;

  // gate (2048 blocks) + fused f2b(W1) (512 blocks)
  gate_kernel<<<2048 + 512, 256, 0, stream>>>(x, Wg, idx, pw, W1, Wbf1, n8w, 2048);
  scan_kernel<<<1, 1024, 0, stream>>>(idx, pw, pos, w, aux);
  dispatch_kernel<<<NSLOT, 128, 0, stream>>>(x, idx, pos, w, Xbf);

  if (big) {
    // GEMM1 (2560 blocks) + fused f2b(W2 -> Wbf2) (256 blocks)
    gemm_bt<<<2560 + 256, 256, 0, stream>>>(Xbf, Wbf1, Hbf, CAP, DFF, DIM, 1,
                                            CAP / 128, 2560, W2, Wbf2, n8w);
    gemm_bt<<<640, 256, 0, stream>>>(Hbf, Wbf2, Ybf, CAP, DIM, DFF, 0,
                                     CAP / 128, 640, nullptr, nullptr, 0);
  } else {
    gemm_bt<<<2560, 256, 0, stream>>>(Xbf, Wbf1, Hbf, CAP, DFF, DIM, 1,
                                      CAP / 128, 2560, nullptr, nullptr, 0);
    f2b_kernel<<<512, 256, 0, stream>>>(W2, Wbf1, n8w);
    gemm_bt<<<640, 256, 0, stream>>>(Hbf, Wbf1, Ybf, CAP, DIM, DFF, 0,
                                     CAP / 128, 640, nullptr, nullptr, 0);
  }
  combine_kernel<<<N_TOK, 128, 0, stream>>>(Ybf, idx, pos, y);
}